// Round 11
// baseline (153.157 us; speedup 1.0000x reference)
//
#include <hip/hip_runtime.h>
#include <hip/hip_bf16.h>

// ---------- types ----------
typedef short bf16x8 __attribute__((ext_vector_type(8)));   // 8 bf16 = 4 VGPR (MFMA A/B frag)
typedef float fx4    __attribute__((ext_vector_type(4)));   // MFMA C/D frag
typedef unsigned uint32x2 __attribute__((ext_vector_type(2)));

#if __has_builtin(__builtin_amdgcn_exp2f)
#define EXP2 __builtin_amdgcn_exp2f
#else
#define EXP2 exp2f
#endif

// packed fp32x2 -> bf16x2 (RNE), emits v_cvt_pk_bf16_f32 on gfx950
__device__ __forceinline__ unsigned pk2(float a, float b) {
  union { __hip_bfloat162 h; unsigned u; } cv;
  cv.h = __float22bfloat162_rn(float2{a, b});
  return cv.u;
}
__device__ __forceinline__ uint2 pk4(const fx4& v) {
  uint2 r;
  r.x = pk2(v[0], v[1]);
  r.y = pk2(v[2], v[3]);
  return r;
}

// async global->LDS, 16B per lane. LDS dest = wave-uniform base + lane*16.
__device__ __forceinline__ void gld16(const void* g, void* l) {
  __builtin_amdgcn_global_load_lds(
      (const __attribute__((address_space(1))) unsigned int*)g,
      (__attribute__((address_space(3))) unsigned int*)l, 16, 0, 0);
}

// ---- barriers that do NOT drain vmcnt (keep register prefetches in flight) ----
__device__ __forceinline__ void bar_raw() {
  asm volatile("s_barrier" ::: "memory");
}
__device__ __forceinline__ void bar_lgkm() {
  asm volatile("s_waitcnt lgkmcnt(0)\ns_barrier" ::: "memory");
}
__device__ __forceinline__ void bar_lgkm_vm12() {
  asm volatile("s_waitcnt vmcnt(12) lgkmcnt(0)\ns_barrier" ::: "memory");
}
// full drain barrier (for gld16 double-buffer handoff in attn)
__device__ __forceinline__ void bar_vm_lgkm() {
  asm volatile("s_waitcnt vmcnt(0) lgkmcnt(0)\ns_barrier" ::: "memory");
}
__device__ __forceinline__ void cfence() { asm volatile("" ::: "memory"); }

// ---------- prep v2: weight transposes ONLY (x-cast folded into gemm_qkv) ----------
__global__ __launch_bounds__(256) void prep_kernel(
    const float* __restrict__ Wq, const float* __restrict__ Wkv,
    const float* __restrict__ Wo,
    short* __restrict__ WallT, short* __restrict__ WoT, float qscale) {
  const int tid = threadIdx.x;
  __shared__ float t[32][33];
  const int idx = blockIdx.x;           // 0..1023
  const int wb = idx & 63, kt = (idx >> 6) * 32;
  const bool mode0 = wb < 48;
  const int ct = (mode0 ? wb : wb - 48) * 32;
  const int tx = tid & 31, ty = tid >> 5;
  short* outT = mode0 ? WallT : WoT;
#pragma unroll
  for (int s = 0; s < 4; ++s) {
    int k = kt + ty + s * 8;
    int c = ct + tx;
    float v;
    if (mode0) v = (c < 512) ? Wq[(size_t)k * 512 + c] * qscale
                             : Wkv[(size_t)k * 1024 + (c - 512)];
    else       v = Wo[(size_t)k * 512 + c];
    t[ty + s * 8][tx] = v;
  }
  __syncthreads();
#pragma unroll
  for (int s = 0; s < 4; ++s) {
    int c = ct + ty + s * 8;
    int k = kt + tx;
    unsigned u = __float_as_uint(t[tx][ty + s * 8]);
    u = (u + 0x7fffu + ((u >> 16) & 1u)) >> 16;
    outT[(size_t)c * 512 + k] = (short)u;
  }
}

// ---------- QKV GEMM v4: fp32-A direct (x-cast fused), coalesced epilogue ----------
// XCD-residency swizzle: 768 blocks flat; xcd = blk&7, each XCD gets 8
// m-panels + the whole B panel -> L2-resident.
// v4 change: A is read DIRECTLY from x (fp32) and converted to bf16 during
// the ds_write (16 v_cvt_pk/thread/iter). Deletes prep's x-cast pass
// (16.8MB read + 8.4MB write + serialized dependency); A fp32 re-reads hit
// L2 (residency swizzle). In-flight after barrier = B(t+1) 4 gld16 +
// A(t+1) 8 float4 = 12 -> vmcnt(12). The ds_write's implicit wait on A(t)
// fp32 loads (newest) still drains B(t) (in-order retirement) => B(t)
// resident for COMPUTE without an explicit wait.
__global__ __launch_bounds__(256) void gemm_qkv(
    const float* __restrict__ Ax, const short* __restrict__ Bt,
    short* __restrict__ oq, short* __restrict__ ok, short* __restrict__ ovT) {
  __shared__ __align__(16) char smem[49152];   // 48 KB
  short* As  = (short*)smem;                   // 8192 shorts (16 KB)
  short* BsA = (short*)(smem + 16384);         // B buf0 (16 KB)
  short* BsB = (short*)(smem + 32768);         // B buf1 (16 KB)
  short* T   = (short*)smem;                   // epilogue overlay: 128x136 shorts
  const int K = 512;
  const int tid = threadIdx.x;
  const int wave = tid >> 6, lane = tid & 63;
  const int quad = lane >> 4, l15 = lane & 15;
  const int wm = wave >> 1, wn = wave & 1;
  const int blk = blockIdx.x;          // 0..767
  const int xcd = blk & 7, slot = blk >> 3;      // slot 0..95
  const int m0 = ((slot / 12) * 8 + xcd) * 128;  // m-tile 0..63
  const int n0 = (slot % 12) * 128;              // n-tile 0..11
  const bool swapped = (n0 < 1024);

  int arow[4], aoff[4];
#pragma unroll
  for (int c = 0; c < 4; ++c) {
    int u = c * 256 + tid;
    int slab = u >> 9, r2 = u & 511;
    arow[c] = r2 >> 2;
    aoff[c] = slab * 32 + (r2 & 3) * 8;
  }

  fx4 acc[4][4];
#pragma unroll
  for (int i = 0; i < 4; ++i)
#pragma unroll
    for (int j = 0; j < 4; ++j) acc[i][j] = fx4{0.f, 0.f, 0.f, 0.f};

  // B DMA for K-step k0 into LDS buffer Bc
  auto BDMA = [&](int k0, short* Bc) {
#pragma unroll
    for (int c = 0; c < 4; ++c) {
      int u = c * 256 + tid;
      int slab = u >> 9, r2 = u & 511;
      gld16(Bt + (size_t)(n0 + (r2 >> 2)) * K + k0 + slab * 32 + (r2 & 3) * 8,
            Bc + (size_t)(c * 256 + wave * 64) * 8);
    }
  };

  // A prefetch for K-step kn: 8 float4 (fp32 x, converted at ds_write time)
  auto APRE = [&](int kn, float4 (&ap)[4][2]) {
#pragma unroll
    for (int c = 0; c < 4; ++c) {
      const float* src = Ax + (size_t)(m0 + arow[c]) * 512 + kn + aoff[c];
      ap[c][0] = *(const float4*)(src);
      ap[c][1] = *(const float4*)(src + 4);
    }
  };

  // ds_write A(t): convert fp32->bf16 packed, one b128 store per c
  auto AWRITE = [&](float4 (&ap)[4][2]) {
#pragma unroll
    for (int c = 0; c < 4; ++c) {
      uint4 w;
      w.x = pk2(ap[c][0].x, ap[c][0].y);
      w.y = pk2(ap[c][0].z, ap[c][0].w);
      w.z = pk2(ap[c][1].x, ap[c][1].y);
      w.w = pk2(ap[c][1].z, ap[c][1].w);
      *(uint4*)(As + (size_t)(c * 256 + tid) * 8) = w;
    }
  };

  auto COMPUTE = [&](const short* Bc) {
#pragma unroll
    for (int ks2 = 0; ks2 < 2; ++ks2) {
      bf16x8 af[4], bfr[4];
#pragma unroll
      for (int i = 0; i < 4; ++i)
        af[i] = *(const bf16x8*)(As + ks2 * 4096 + (wm * 64 + i * 16 + l15) * 32 + quad * 8);
#pragma unroll
      for (int i = 0; i < 4; ++i)
        bfr[i] = *(const bf16x8*)(Bc + ks2 * 4096 + (wn * 64 + i * 16 + l15) * 32 + quad * 8);
      if (swapped) {
#pragma unroll
        for (int mi = 0; mi < 4; ++mi)
#pragma unroll
          for (int ni = 0; ni < 4; ++ni)
            acc[mi][ni] = __builtin_amdgcn_mfma_f32_16x16x32_bf16(bfr[ni], af[mi], acc[mi][ni], 0, 0, 0);
      } else {
#pragma unroll
        for (int mi = 0; mi < 4; ++mi)
#pragma unroll
          for (int ni = 0; ni < 4; ++ni)
            acc[mi][ni] = __builtin_amdgcn_mfma_f32_16x16x32_bf16(af[mi], bfr[ni], acc[mi][ni], 0, 0, 0);
      }
    }
  };

  // prologue: B(0) first (oldest in vmcnt order), then A(0) fp32 regs
  BDMA(0, BsA);
  cfence();
  float4 apre[4][2];
  APRE(0, apre);

  for (int t = 0; t < 7; ++t) {
    bar_raw();                         // all waves done reading As / other B buf
    AWRITE(apre);                      // implicit wait on A(t) => B(t) resident
    BDMA((t + 1) * 64, ((t + 1) & 1) ? BsB : BsA);   // B(t+1), full iter to land
    cfence();
    APRE((t + 1) * 64, apre);
    bar_lgkm_vm12();                   // keep B(t+1)+A(t+1) (12 newest) in flight
    COMPUTE((t & 1) ? BsB : BsA);
  }
  // t = 7
  bar_raw();
  AWRITE(apre);
  bar_lgkm();
  COMPUTE(BsB);

  // ---------- coalesced epilogue via LDS transpose tile ----------
  const int cls = n0 >> 9;             // 0=q, 1=k, 2=v
  const int fbase = n0 & 511;          // feature base (multiple of 128)
  const int bb = m0 >> 11;             // batch index (constant across tile)
  const int iib = m0 & 2047;           // token base within batch

  bar_lgkm();                          // all waves done with As/Bs before T overlay
  if (cls < 2) {
    // T[m][c]: acc holds C^T (row=f via quad*4+r, col=m via l15)
#pragma unroll
    for (int mi = 0; mi < 4; ++mi) {
      int bl_m = wm * 64 + mi * 16 + l15;
#pragma unroll
      for (int ni = 0; ni < 4; ++ni) {
        int bl_c = wn * 64 + ni * 16 + quad * 4;
        *(uint2*)(T + bl_m * 136 + bl_c) = pk4(acc[mi][ni]);
      }
    }
    bar_lgkm();                        // T writes visible to all waves
    short* base = (cls == 0) ? oq : ok;
#pragma unroll
    for (int p = 0; p < 8; ++p) {
      int u = p * 256 + tid;
      int row = u >> 4, c0 = (u & 15) * 8;
      int f = fbase + c0;
      int hh = f >> 6, dd = f & 63;
      uint4 v = *(const uint4*)(T + row * 136 + c0);
      *(uint4*)(base + ((size_t)(bb * 8 + hh) * 2048 + iib + row) * 64 + dd) = v;
    }
  } else {
    // T2[c][m]: acc holds C (row=m via quad*4+r, col=f via l15)
#pragma unroll
    for (int mi = 0; mi < 4; ++mi) {
      int bl_m = wm * 64 + mi * 16 + quad * 4;
#pragma unroll
      for (int ni = 0; ni < 4; ++ni) {
        int bl_c = wn * 64 + ni * 16 + l15;
        *(uint2*)(T + bl_c * 136 + bl_m) = pk4(acc[mi][ni]);
      }
    }
    bar_lgkm();
#pragma unroll
    for (int p = 0; p < 8; ++p) {
      int u = p * 256 + tid;
      int c = u >> 4, m8 = (u & 15) * 8;
      int f = fbase + c;
      int hh = f >> 6, dd = f & 63;
      uint4 v = *(const uint4*)(T + c * 136 + m8);
      *(uint4*)(ovT + ((size_t)(bb * 8 + hh) * 64 + dd) * 2048 + iib + m8) = v;
    }
  }
}

// ---------- out-proj GEMM: 64x128 tile, BK=64, full reg-prefetch, fp32+bias ----------
__global__ __launch_bounds__(256) void gemm_out(
    const short* __restrict__ A, const short* __restrict__ Bt,
    float* __restrict__ of, const float* __restrict__ bias) {
  __shared__ short As[2 * 64 * 32];    // 8KB
  __shared__ short Bs[2 * 128 * 32];   // 16KB
  const int K = 512, N = 512;
  const int tid = threadIdx.x;
  const int wave = tid >> 6, lane = tid & 63;
  const int quad = lane >> 4, l15 = lane & 15;
  const int wm = wave >> 1, wn = wave & 1;
  const int m0 = blockIdx.y * 64, n0 = blockIdx.x * 128;

  int arow[2], aoff[2], brow[4], boff[4];
#pragma unroll
  for (int c = 0; c < 2; ++c) {
    int u = c * 256 + tid;
    int slab = u >> 8, r2 = u & 255;
    arow[c] = r2 >> 2; aoff[c] = slab * 32 + (r2 & 3) * 8;
  }
#pragma unroll
  for (int c = 0; c < 4; ++c) {
    int u = c * 256 + tid;
    int slab = u >> 9, r2 = u & 511;
    brow[c] = r2 >> 2; boff[c] = slab * 32 + (r2 & 3) * 8;
  }

  fx4 acc[2][4];
#pragma unroll
  for (int i = 0; i < 2; ++i)
#pragma unroll
    for (int j = 0; j < 4; ++j) acc[i][j] = fx4{0.f, 0.f, 0.f, 0.f};

  bf16x8 apre[2], bpre[4];
#pragma unroll
  for (int c = 0; c < 2; ++c)
    apre[c] = *(const bf16x8*)(A + (size_t)(m0 + arow[c]) * K + aoff[c]);
#pragma unroll
  for (int c = 0; c < 4; ++c)
    bpre[c] = *(const bf16x8*)(Bt + (size_t)(n0 + brow[c]) * K + boff[c]);

  for (int k0 = 0; k0 < K; k0 += 64) {
    bar_raw();
#pragma unroll
    for (int c = 0; c < 2; ++c)
      *(bf16x8*)(As + (size_t)(c * 256 + tid) * 8) = apre[c];
#pragma unroll
    for (int c = 0; c < 4; ++c)
      *(bf16x8*)(Bs + (size_t)(c * 256 + tid) * 8) = bpre[c];
    {
      int kn = (k0 + 64) & 511;
#pragma unroll
      for (int c = 0; c < 2; ++c)
        apre[c] = *(const bf16x8*)(A + (size_t)(m0 + arow[c]) * K + kn + aoff[c]);
#pragma unroll
      for (int c = 0; c < 4; ++c)
        bpre[c] = *(const bf16x8*)(Bt + (size_t)(n0 + brow[c]) * K + kn + boff[c]);
    }
    bar_lgkm();

#pragma unroll
    for (int ks2 = 0; ks2 < 2; ++ks2) {
      bf16x8 af[2], bfr[4];
#pragma unroll
      for (int i = 0; i < 2; ++i)
        af[i] = *(const bf16x8*)(As + ks2 * 2048 + (wm * 32 + i * 16 + l15) * 32 + quad * 8);
#pragma unroll
      for (int i = 0; i < 4; ++i)
        bfr[i] = *(const bf16x8*)(Bs + ks2 * 4096 + (wn * 64 + i * 16 + l15) * 32 + quad * 8);
#pragma unroll
      for (int mi = 0; mi < 2; ++mi)
#pragma unroll
        for (int ni = 0; ni < 4; ++ni)
          acc[mi][ni] = __builtin_amdgcn_mfma_f32_16x16x32_bf16(af[mi], bfr[ni], acc[mi][ni], 0, 0, 0);
    }
  }

  const int rowb = m0 + wm * 32;
  const int colb = n0 + wn * 64;
#pragma unroll
  for (int mi = 0; mi < 2; ++mi)
#pragma unroll
    for (int ni = 0; ni < 4; ++ni) {
      int cg = colb + ni * 16 + l15;
      float bv = bias[cg];
#pragma unroll
      for (int r = 0; r < 4; ++r) {
        int rg = rowb + mi * 16 + quad * 4 + r;
        of[(size_t)rg * N + cg] = acc[mi][ni][r] + bv;
      }
    }
}

// ---------- flash attention v5 (best: ~50us): cross-tile software pipeline ----------
// Q,K: [bh=32][2048][64] bf16 ; Vt: [bh][64][2048] bf16 ; O: [b][2048][512] bf16
// Iteration t runs QK^T(t) [MFMA, LDS] concurrently with softmax(t-1) [VALU,
// regs] and PV(t-1) [MFMA, regs]. V register-carried (dual vfA/vfB). One
// full-drain barrier per tile; DMA issued right after it gets the whole phase
// to land (L2-resident via XCD residency swizzle).
__global__ __launch_bounds__(256, 2) void attn_kernel(
    const short* __restrict__ Q, const short* __restrict__ K,
    const short* __restrict__ Vt, short* __restrict__ O) {
  __shared__ short Ks[2 * 64 * 64];    // [buf][j][d], seg-swizzled (seg ^ row&7)
  __shared__ short Vs[2 * 64 * 64];    // [buf][d][j], seg-swizzled

  const int tid = threadIdx.x;
  const int wave = tid >> 6, lane = tid & 63;
  const int quad = lane >> 4, l15 = lane & 15;
  const int blk = blockIdx.x;          // 0..511
  const int xcd = blk & 7, slot = blk >> 3;   // slot 0..63
  const int bh = (slot >> 4) * 8 + xcd;       // 4 bh-groups per XCD (L2-resident K/V)
  const int qt = slot & 15;                   // 16 q-tiles per bh
  const int b = bh >> 3, h = bh & 7;
  const int i0 = qt * 128 + wave * 32;

  const int idx0 = tid, idx1 = 256 + tid;
  const int row0 = idx0 >> 3, sg0 = (idx0 & 7) ^ (row0 & 7);
  const int row1 = idx1 >> 3, sg1 = (idx1 & 7) ^ (row1 & 7);
  const short* Kb = K + (size_t)bh * 2048 * 64;
  const short* Vb = Vt + (size_t)bh * 64 * 2048;

  // Q as B-operand fragments: [it][ks]; i = it*16+l15, d = ks*32+quad*8+e
  bf16x8 qf[2][2];
#pragma unroll
  for (int it = 0; it < 2; ++it)
#pragma unroll
    for (int ks = 0; ks < 2; ++ks)
      qf[it][ks] = *(const bf16x8*)(Q + ((size_t)bh * 2048 + i0 + it * 16 + l15) * 64 + ks * 32 + quad * 8);

  bf16x8 ones;
#pragma unroll
  for (int c = 0; c < 8; ++c) ones[c] = (short)0x3F80;

  fx4 oacc[2][4];                      // [it][dt], O^T: row d=quad*4+r, col i=l15
  fx4 acc_l[2] = { fx4{0.f,0.f,0.f,0.f}, fx4{0.f,0.f,0.f,0.f} };
#pragma unroll
  for (int it = 0; it < 2; ++it)
#pragma unroll
    for (int dt = 0; dt < 4; ++dt) oacc[it][dt] = fx4{0.f, 0.f, 0.f, 0.f};

  // DMA one j-tile (K 8KB + V 8KB) into buffer bufsel; LDS dest linear,
  // global src pre-swizzled (seg ^ row&7) so LDS layout lands swizzled.
  auto DMA = [&](int jn, int bufsel) {
    const int nb = bufsel * 4096;
    gld16(Kb + (size_t)(jn + row0) * 64 + sg0 * 8, Ks + nb + wave * 512);
    gld16(Kb + (size_t)(jn + row1) * 64 + sg1 * 8, Ks + nb + 2048 + wave * 512);
    gld16(Vb + (size_t)row0 * 2048 + jn + sg0 * 8, Vs + nb + wave * 512);
    gld16(Vb + (size_t)row1 * 2048 + jn + sg1 * 8, Vs + nb + 2048 + wave * 512);
  };

  // S^T(t) = K·Q^T from LDS buffer into named reg tile s[2][4]
  auto QK = [&](const short* Kc, fx4 (&s)[2][4]) {
#pragma unroll
    for (int it = 0; it < 2; ++it)
#pragma unroll
      for (int jt = 0; jt < 4; ++jt) s[it][jt] = fx4{0.f, 0.f, 0.f, 0.f};
#pragma unroll
    for (int ks = 0; ks < 2; ++ks) {
#pragma unroll
      for (int jt = 0; jt < 4; ++jt) {
        bf16x8 kf = *(const bf16x8*)(Kc + (jt * 16 + l15) * 64 + (((ks * 4 + quad) ^ (l15 & 7)) * 8));
#pragma unroll
        for (int it = 0; it < 2; ++it)
          s[it][jt] = __builtin_amdgcn_mfma_f32_16x16x32_bf16(kf, qf[it][ks], s[it][jt], 0, 0, 0);
      }
    }
  };

  // V fragments tile t -> registers (so PV(t) can run while DMA(t+2) owns LDS)
  auto VLOAD = [&](const short* Vc, bf16x8 (&vf)[2][4]) {
#pragma unroll
    for (int kj = 0; kj < 2; ++kj)
#pragma unroll
      for (int dt = 0; dt < 4; ++dt)
        vf[kj][dt] = *(const bf16x8*)(Vc + (dt * 16 + l15) * 64 + (((kj * 4 + quad) ^ (l15 & 7)) * 8));
  };

  // softmax + butterfly + PV of a PREVIOUS tile, all register operands
  auto SMPV = [&](fx4 (&s)[2][4], bf16x8 (&vf)[2][4]) {
#pragma unroll
    for (int it = 0; it < 2; ++it) {
      unsigned W[4][2];                // [jt][h]: bf16x2 of j = 16jt+4q+2h,+1
#pragma unroll
      for (int jt = 0; jt < 4; ++jt) {
#pragma unroll
        for (int r = 0; r < 4; ++r) s[it][jt][r] = EXP2(s[it][jt][r]);
        W[jt][0] = pk2(s[it][jt][0], s[it][jt][1]);
        W[jt][1] = pk2(s[it][jt][2], s[it][jt][3]);
      }
#pragma unroll
      for (int k = 0; k < 2; ++k) {    // k = kj = b5
        union { unsigned u[4]; bf16x8 v; } pw;
#pragma unroll
        for (int hh = 0; hh < 2; ++hh) {  // hh = b1
          uint32x2 a = __builtin_amdgcn_permlane32_swap(W[2 * k][hh], W[2 * k + 1][hh], false, false);
          uint32x2 t = __builtin_amdgcn_permlane16_swap(a[0], a[1], false, false);
          pw.u[hh] = t[0];             // b2=0 -> word m=hh
          pw.u[2 + hh] = t[1];         // b2=1 -> word m=2+hh
        }
        acc_l[it] = __builtin_amdgcn_mfma_f32_16x16x32_bf16(ones, pw.v, acc_l[it], 0, 0, 0);
#pragma unroll
        for (int dt = 0; dt < 4; ++dt)
          oacc[it][dt] = __builtin_amdgcn_mfma_f32_16x16x32_bf16(vf[k][dt], pw.v, oacc[it][dt], 0, 0, 0);
      }
    }
  };

  fx4 sA[2][4], sB[2][4];
  bf16x8 vfA[2][4], vfB[2][4];

  // prologue: tile0 -> buf0; start tile1 -> buf1; QK(0)
  DMA(0, 0);
  bar_vm_lgkm();                       // tile0 resident
  DMA(64, 1);
  QK(Ks, sA);
  VLOAD(Vs, vfA);

  // steady state: 15 iterations handle tiles 1..30 (QK) / 0..29 (SMPV)
  for (int t1 = 1; t1 <= 29; t1 += 2) {
    bar_vm_lgkm();                     // tile t1 (buf1) resident; buf0 reads drained
    DMA((t1 + 1) << 6, 0);             // tile t1+1 -> buf0
    QK(Ks + 4096, sB);                 // MFMA stream: QK(t1)
    VLOAD(Vs + 4096, vfB);
    SMPV(sA, vfA);                     // VALU+MFMA stream: finish tile t1-1
    bar_vm_lgkm();                     // tile t1+1 (buf0) resident; buf1 reads drained
    DMA((t1 + 2) << 6, 1);             // tile t1+2 -> buf1 (t1=29 -> tile31)
    QK(Ks, sA);                        // QK(t1+1)
    VLOAD(Vs, vfA);
    SMPV(sB, vfB);                     // finish tile t1
  }

  // tail: tile31
  bar_vm_lgkm();                       // tile31 (buf1) resident
  QK(Ks + 4096, sB);
  VLOAD(Vs + 4096, vfB);
  SMPV(sA, vfA);                       // finish tile 30
  SMPV(sB, vfB);                       // finish tile 31

  // ---- normalize + write O bf16 [b][n=i][h*64+d]; 4 consecutive d -> b64 ----
#pragma unroll
  for (int it = 0; it < 2; ++it) {
    float inv = __builtin_amdgcn_rcpf(acc_l[it][0]);
    size_t rowbase = ((size_t)b * 2048 + i0 + it * 16 + l15) * 512 + h * 64;
#pragma unroll
    for (int dt = 0; dt < 4; ++dt) {
      fx4 o = oacc[it][dt] * inv;
      *(uint2*)(O + rowbase + dt * 16 + quad * 4) = pk4(o);
    }
  }
}

// ---------- launch ----------
extern "C" void kernel_launch(void* const* d_in, const int* in_sizes, int n_in,
                              void* d_out, int out_size, void* d_ws, size_t ws_size,
                              hipStream_t stream) {
  const float* x   = (const float*)d_in[0];
  const float* Wq  = (const float*)d_in[1];
  const float* Wkv = (const float*)d_in[2];
  const float* Wo  = (const float*)d_in[3];
  const float* bo  = (const float*)d_in[4];
  float* out = (float*)d_out;

  char* p = (char*)d_ws;
  short* WallT = (short*)p; p += (size_t)1536 * 512 * 2;   // [Wq|Wkv]^T bf16 [1536,512]
  short* WoT   = (short*)p; p += (size_t)512 * 512 * 2;    // Wo^T bf16 [512,512]
  short* qb    = (short*)p; p += (size_t)32 * 2048 * 64 * 2;  // [bh,n,d]
  short* kb    = (short*)p; p += (size_t)32 * 2048 * 64 * 2;  // [bh,n,d]
  short* vTb   = (short*)p; p += (size_t)32 * 64 * 2048 * 2;  // [bh,d,n]
  short* Ob    = (short*)p; p += (size_t)8192 * 512 * 2;   // attn out bf16 [8192,512]

  const float qscale = 0.125f * 1.4426950408889634f;  // d^-0.5 * log2(e)

  prep_kernel<<<1024, 256, 0, stream>>>(Wq, Wkv, Wo, WallT, WoT, qscale);
  gemm_qkv<<<768, 256, 0, stream>>>(x, WallT, qb, kb, vTb);
  attn_kernel<<<512, 256, 0, stream>>>(qb, kb, vTb, Ob);
  gemm_out<<<dim3(4, 128), 256, 0, stream>>>(Ob, WoT, out, bo);
}

// Round 13
// 150.898 us; speedup vs baseline: 1.0150x; 1.0150x over previous
//
#include <hip/hip_runtime.h>
#include <hip/hip_cooperative_groups.h>
#include <hip/hip_bf16.h>

namespace cg = cooperative_groups;

// ---------- types ----------
typedef short bf16x8 __attribute__((ext_vector_type(8)));   // 8 bf16 = 4 VGPR (MFMA A/B frag)
typedef float fx4    __attribute__((ext_vector_type(4)));   // MFMA C/D frag
typedef unsigned uint32x2 __attribute__((ext_vector_type(2)));

#if __has_builtin(__builtin_amdgcn_exp2f)
#define EXP2 __builtin_amdgcn_exp2f
#else
#define EXP2 exp2f
#endif

// packed fp32x2 -> bf16x2 (RNE), emits v_cvt_pk_bf16_f32 on gfx950
__device__ __forceinline__ unsigned pk2(float a, float b) {
  union { __hip_bfloat162 h; unsigned u; } cv;
  cv.h = __float22bfloat162_rn(float2{a, b});
  return cv.u;
}
__device__ __forceinline__ uint2 pk4(const fx4& v) {
  uint2 r;
  r.x = pk2(v[0], v[1]);
  r.y = pk2(v[2], v[3]);
  return r;
}

// async global->LDS, 16B per lane. LDS dest = wave-uniform base + lane*16.
__device__ __forceinline__ void gld16(const void* g, void* l) {
  __builtin_amdgcn_global_load_lds(
      (const __attribute__((address_space(1))) unsigned int*)g,
      (__attribute__((address_space(3))) unsigned int*)l, 16, 0, 0);
}

// ---- barriers that do NOT drain vmcnt (keep register prefetches in flight) ----
__device__ __forceinline__ void bar_raw() {
  asm volatile("s_barrier" ::: "memory");
}
__device__ __forceinline__ void bar_lgkm() {
  asm volatile("s_waitcnt lgkmcnt(0)\ns_barrier" ::: "memory");
}
__device__ __forceinline__ void bar_lgkm_vm8() {
  asm volatile("s_waitcnt vmcnt(8) lgkmcnt(0)\ns_barrier" ::: "memory");
}
// full drain barrier (for gld16 double-buffer handoff in attn)
__device__ __forceinline__ void bar_vm_lgkm() {
  asm volatile("s_waitcnt vmcnt(0) lgkmcnt(0)\ns_barrier" ::: "memory");
}
__device__ __forceinline__ void cfence() { asm volatile("" ::: "memory"); }

// =======================================================================
// ===============  Shared phase bodies (R10, verbatim)  =================
// =======================================================================

// ---- prep body: one virtual block vb in [0,5120) ----
__device__ __forceinline__ void prep_body(
    int vb, int tid, void* smem,
    const float* __restrict__ x, const float* __restrict__ Wq,
    const float* __restrict__ Wkv, const float* __restrict__ Wo,
    short* __restrict__ xb, short* __restrict__ WallT, short* __restrict__ WoT,
    float qscale) {
  if (vb < 4096) {
    int i = vb * 256 + tid;
    const float4 s = *(const float4*)(x + (size_t)i * 4);
    uint2 o; o.x = pk2(s.x, s.y); o.y = pk2(s.z, s.w);
    *(uint2*)(xb + (size_t)i * 4) = o;
    return;
  }
  float (*t)[33] = (float(*)[33])smem;
  const int idx = vb - 4096;            // 0..1023
  const int wb = idx & 63, kt = (idx >> 6) * 32;
  const bool mode0 = wb < 48;
  const int ct = (mode0 ? wb : wb - 48) * 32;
  const int tx = tid & 31, ty = tid >> 5;
  short* outT = mode0 ? WallT : WoT;
  __syncthreads();                      // protect t from prior tile's readers
#pragma unroll
  for (int s = 0; s < 4; ++s) {
    int k = kt + ty + s * 8;
    int c = ct + tx;
    float v;
    if (mode0) v = (c < 512) ? Wq[(size_t)k * 512 + c] * qscale
                             : Wkv[(size_t)k * 1024 + (c - 512)];
    else       v = Wo[(size_t)k * 512 + c];
    t[ty + s * 8][tx] = v;
  }
  __syncthreads();
#pragma unroll
  for (int s = 0; s < 4; ++s) {
    int c = ct + ty + s * 8;
    int k = kt + tx;
    unsigned u = __float_as_uint(t[tx][ty + s * 8]);
    u = (u + 0x7fffu + ((u >> 16) & 1u)) >> 16;
    outT[(size_t)c * 512 + k] = (short)u;
  }
}

// ---- QKV GEMM body (R10 v3): blk in [0,768), smem >= 48KB ----
__device__ __forceinline__ void qkv_body(
    int blk, int tid, char* smem,
    const short* __restrict__ A, const short* __restrict__ Bt,
    short* __restrict__ oq, short* __restrict__ ok, short* __restrict__ ovT) {
  short* As  = (short*)smem;                   // 16 KB
  short* BsA = (short*)(smem + 16384);         // 16 KB
  short* BsB = (short*)(smem + 32768);         // 16 KB
  short* T   = (short*)smem;                   // epilogue overlay 128x136
  const int K = 512;
  const int wave = tid >> 6, lane = tid & 63;
  const int quad = lane >> 4, l15 = lane & 15;
  const int wm = wave >> 1, wn = wave & 1;
  const int xcd = blk & 7, slot = blk >> 3;    // slot 0..95
  const int m0 = ((slot / 12) * 8 + xcd) * 128;
  const int n0 = (slot % 12) * 128;
  const bool swapped = (n0 < 1024);

  int arow[4], aoff[4];
#pragma unroll
  for (int c = 0; c < 4; ++c) {
    int u = c * 256 + tid;
    int slab = u >> 9, r2 = u & 511;
    arow[c] = r2 >> 2;
    aoff[c] = slab * 32 + (r2 & 3) * 8;
  }

  fx4 acc[4][4];
#pragma unroll
  for (int i = 0; i < 4; ++i)
#pragma unroll
    for (int j = 0; j < 4; ++j) acc[i][j] = fx4{0.f, 0.f, 0.f, 0.f};

  auto BDMA = [&](int k0, short* Bc) {
#pragma unroll
    for (int c = 0; c < 4; ++c) {
      int u = c * 256 + tid;
      int slab = u >> 9, r2 = u & 511;
      gld16(Bt + (size_t)(n0 + (r2 >> 2)) * K + k0 + slab * 32 + (r2 & 3) * 8,
            Bc + (size_t)(c * 256 + wave * 64) * 8);
    }
  };

  auto COMPUTE = [&](const short* Bc) {
#pragma unroll
    for (int ks2 = 0; ks2 < 2; ++ks2) {
      bf16x8 af[4], bfr[4];
#pragma unroll
      for (int i = 0; i < 4; ++i)
        af[i] = *(const bf16x8*)(As + ks2 * 4096 + (wm * 64 + i * 16 + l15) * 32 + quad * 8);
#pragma unroll
      for (int i = 0; i < 4; ++i)
        bfr[i] = *(const bf16x8*)(Bc + ks2 * 4096 + (wn * 64 + i * 16 + l15) * 32 + quad * 8);
      if (swapped) {
#pragma unroll
        for (int mi = 0; mi < 4; ++mi)
#pragma unroll
          for (int ni = 0; ni < 4; ++ni)
            acc[mi][ni] = __builtin_amdgcn_mfma_f32_16x16x32_bf16(bfr[ni], af[mi], acc[mi][ni], 0, 0, 0);
      } else {
#pragma unroll
        for (int mi = 0; mi < 4; ++mi)
#pragma unroll
          for (int ni = 0; ni < 4; ++ni)
            acc[mi][ni] = __builtin_amdgcn_mfma_f32_16x16x32_bf16(af[mi], bfr[ni], acc[mi][ni], 0, 0, 0);
      }
    }
  };

  // prologue: B(0) first (oldest in vmcnt order), then A(0) regs
  BDMA(0, BsA);
  cfence();
  bf16x8 apre[4];
#pragma unroll
  for (int c = 0; c < 4; ++c)
    apre[c] = *(const bf16x8*)(A + (size_t)(m0 + arow[c]) * K + aoff[c]);

  for (int t = 0; t < 7; ++t) {
    bar_raw();                         // all waves done reading As / other B buf
#pragma unroll
    for (int c = 0; c < 4; ++c)        // implicit wait on A(t) => B(t) resident
      *(bf16x8*)(As + (size_t)(c * 256 + tid) * 8) = apre[c];
    BDMA((t + 1) * 64, ((t + 1) & 1) ? BsB : BsA);   // B(t+1), full iter to land
    cfence();
    {
      int kn = (t + 1) * 64;
#pragma unroll
      for (int c = 0; c < 4; ++c)
        apre[c] = *(const bf16x8*)(A + (size_t)(m0 + arow[c]) * K + kn + aoff[c]);
    }
    bar_lgkm_vm8();                    // keep B(t+1)+A(t+1) (8 newest) in flight
    COMPUTE((t & 1) ? BsB : BsA);
  }
  // t = 7
  bar_raw();
#pragma unroll
  for (int c = 0; c < 4; ++c)
    *(bf16x8*)(As + (size_t)(c * 256 + tid) * 8) = apre[c];
  bar_lgkm();
  COMPUTE(BsB);

  // ---------- coalesced epilogue via LDS transpose tile ----------
  const int cls = n0 >> 9;             // 0=q, 1=k, 2=v
  const int fbase = n0 & 511;
  const int bb = m0 >> 11;
  const int iib = m0 & 2047;

  bar_lgkm();                          // all waves done with As/Bs before T overlay
  if (cls < 2) {
#pragma unroll
    for (int mi = 0; mi < 4; ++mi) {
      int bl_m = wm * 64 + mi * 16 + l15;
#pragma unroll
      for (int ni = 0; ni < 4; ++ni) {
        int bl_c = wn * 64 + ni * 16 + quad * 4;
        *(uint2*)(T + bl_m * 136 + bl_c) = pk4(acc[mi][ni]);
      }
    }
    bar_lgkm();
    short* base = (cls == 0) ? oq : ok;
#pragma unroll
    for (int p = 0; p < 8; ++p) {
      int u = p * 256 + tid;
      int row = u >> 4, c0 = (u & 15) * 8;
      int f = fbase + c0;
      int hh = f >> 6, dd = f & 63;
      uint4 v = *(const uint4*)(T + row * 136 + c0);
      *(uint4*)(base + ((size_t)(bb * 8 + hh) * 2048 + iib + row) * 64 + dd) = v;
    }
  } else {
#pragma unroll
    for (int mi = 0; mi < 4; ++mi) {
      int bl_m = wm * 64 + mi * 16 + quad * 4;
#pragma unroll
      for (int ni = 0; ni < 4; ++ni) {
        int bl_c = wn * 64 + ni * 16 + l15;
        *(uint2*)(T + bl_c * 136 + bl_m) = pk4(acc[mi][ni]);
      }
    }
    bar_lgkm();
#pragma unroll
    for (int p = 0; p < 8; ++p) {
      int u = p * 256 + tid;
      int c = u >> 4, m8 = (u & 15) * 8;
      int f = fbase + c;
      int hh = f >> 6, dd = f & 63;
      uint4 v = *(const uint4*)(T + c * 136 + m8);
      *(uint4*)(ovT + ((size_t)(bb * 8 + hh) * 64 + dd) * 2048 + iib + m8) = v;
    }
  }
}

// ---- attn body (R10 v5): blk in [0,512), smem >= 32KB ----
__device__ __forceinline__ void attn_body(
    int blk, int tid, char* smem,
    const short* __restrict__ Q, const short* __restrict__ Kq,
    const short* __restrict__ Vt, short* __restrict__ O) {
  short* Ks = (short*)smem;            // [buf][j][d], seg-swizzled
  short* Vs = (short*)(smem + 16384);  // [buf][d][j], seg-swizzled
  const int wave = tid >> 6, lane = tid & 63;
  const int quad = lane >> 4, l15 = lane & 15;
  const int xcd = blk & 7, slot = blk >> 3;
  const int bh = (slot >> 4) * 8 + xcd;
  const int qt = slot & 15;
  const int b = bh >> 3, h = bh & 7;
  const int i0 = qt * 128 + wave * 32;

  const int idx0 = tid, idx1 = 256 + tid;
  const int row0 = idx0 >> 3, sg0 = (idx0 & 7) ^ (row0 & 7);
  const int row1 = idx1 >> 3, sg1 = (idx1 & 7) ^ (row1 & 7);
  const short* Kb = Kq + (size_t)bh * 2048 * 64;
  const short* Vb = Vt + (size_t)bh * 64 * 2048;

  bf16x8 qf[2][2];
#pragma unroll
  for (int it = 0; it < 2; ++it)
#pragma unroll
    for (int ks = 0; ks < 2; ++ks)
      qf[it][ks] = *(const bf16x8*)(Q + ((size_t)bh * 2048 + i0 + it * 16 + l15) * 64 + ks * 32 + quad * 8);

  bf16x8 ones;
#pragma unroll
  for (int c = 0; c < 8; ++c) ones[c] = (short)0x3F80;

  fx4 oacc[2][4];
  fx4 acc_l[2] = { fx4{0.f,0.f,0.f,0.f}, fx4{0.f,0.f,0.f,0.f} };
#pragma unroll
  for (int it = 0; it < 2; ++it)
#pragma unroll
    for (int dt = 0; dt < 4; ++dt) oacc[it][dt] = fx4{0.f, 0.f, 0.f, 0.f};

  auto DMA = [&](int jn, int bufsel) {
    const int nb = bufsel * 4096;
    gld16(Kb + (size_t)(jn + row0) * 64 + sg0 * 8, Ks + nb + wave * 512);
    gld16(Kb + (size_t)(jn + row1) * 64 + sg1 * 8, Ks + nb + 2048 + wave * 512);
    gld16(Vb + (size_t)row0 * 2048 + jn + sg0 * 8, Vs + nb + wave * 512);
    gld16(Vb + (size_t)row1 * 2048 + jn + sg1 * 8, Vs + nb + 2048 + wave * 512);
  };

  auto QK = [&](const short* Kc, fx4 (&s)[2][4]) {
#pragma unroll
    for (int it = 0; it < 2; ++it)
#pragma unroll
      for (int jt = 0; jt < 4; ++jt) s[it][jt] = fx4{0.f, 0.f, 0.f, 0.f};
#pragma unroll
    for (int ks = 0; ks < 2; ++ks) {
#pragma unroll
      for (int jt = 0; jt < 4; ++jt) {
        bf16x8 kf = *(const bf16x8*)(Kc + (jt * 16 + l15) * 64 + (((ks * 4 + quad) ^ (l15 & 7)) * 8));
#pragma unroll
        for (int it = 0; it < 2; ++it)
          s[it][jt] = __builtin_amdgcn_mfma_f32_16x16x32_bf16(kf, qf[it][ks], s[it][jt], 0, 0, 0);
      }
    }
  };

  auto VLOAD = [&](const short* Vc, bf16x8 (&vf)[2][4]) {
#pragma unroll
    for (int kj = 0; kj < 2; ++kj)
#pragma unroll
      for (int dt = 0; dt < 4; ++dt)
        vf[kj][dt] = *(const bf16x8*)(Vc + (dt * 16 + l15) * 64 + (((kj * 4 + quad) ^ (l15 & 7)) * 8));
  };

  auto SMPV = [&](fx4 (&s)[2][4], bf16x8 (&vf)[2][4]) {
#pragma unroll
    for (int it = 0; it < 2; ++it) {
      unsigned W[4][2];
#pragma unroll
      for (int jt = 0; jt < 4; ++jt) {
#pragma unroll
        for (int r = 0; r < 4; ++r) s[it][jt][r] = EXP2(s[it][jt][r]);
        W[jt][0] = pk2(s[it][jt][0], s[it][jt][1]);
        W[jt][1] = pk2(s[it][jt][2], s[it][jt][3]);
      }
#pragma unroll
      for (int k = 0; k < 2; ++k) {
        union { unsigned u[4]; bf16x8 v; } pw;
#pragma unroll
        for (int hh = 0; hh < 2; ++hh) {
          uint32x2 a = __builtin_amdgcn_permlane32_swap(W[2 * k][hh], W[2 * k + 1][hh], false, false);
          uint32x2 t = __builtin_amdgcn_permlane16_swap(a[0], a[1], false, false);
          pw.u[hh] = t[0];
          pw.u[2 + hh] = t[1];
        }
        acc_l[it] = __builtin_amdgcn_mfma_f32_16x16x32_bf16(ones, pw.v, acc_l[it], 0, 0, 0);
#pragma unroll
        for (int dt = 0; dt < 4; ++dt)
          oacc[it][dt] = __builtin_amdgcn_mfma_f32_16x16x32_bf16(vf[k][dt], pw.v, oacc[it][dt], 0, 0, 0);
      }
    }
  };

  fx4 sA[2][4], sB[2][4];
  bf16x8 vfA[2][4], vfB[2][4];

  DMA(0, 0);
  bar_vm_lgkm();                       // tile0 resident
  DMA(64, 1);
  QK(Ks, sA);
  VLOAD(Vs, vfA);

  for (int t1 = 1; t1 <= 29; t1 += 2) {
    bar_vm_lgkm();                     // tile t1 (buf1) resident
    DMA((t1 + 1) << 6, 0);
    QK(Ks + 4096, sB);
    VLOAD(Vs + 4096, vfB);
    SMPV(sA, vfA);
    bar_vm_lgkm();                     // tile t1+1 (buf0) resident
    DMA((t1 + 2) << 6, 1);
    QK(Ks, sA);
    VLOAD(Vs, vfA);
    SMPV(sB, vfB);
  }

  bar_vm_lgkm();                       // tile31 resident
  QK(Ks + 4096, sB);
  VLOAD(Vs + 4096, vfB);
  SMPV(sA, vfA);
  SMPV(sB, vfB);

#pragma unroll
  for (int it = 0; it < 2; ++it) {
    float inv = __builtin_amdgcn_rcpf(acc_l[it][0]);
    size_t rowbase = ((size_t)b * 2048 + i0 + it * 16 + l15) * 512 + h * 64;
#pragma unroll
    for (int dt = 0; dt < 4; ++dt) {
      fx4 o = oacc[it][dt] * inv;
      *(uint2*)(O + rowbase + dt * 16 + quad * 4) = pk4(o);
    }
  }
}

// ---- out-proj body (R10): vb in [0,512), smem >= 24KB ----
__device__ __forceinline__ void out_body(
    int vb, int tid, char* smem,
    const short* __restrict__ A, const short* __restrict__ Bt,
    float* __restrict__ of, const float* __restrict__ bias) {
  short* As = (short*)smem;            // 8 KB
  short* Bs = (short*)(smem + 8192);   // 16 KB
  const int K = 512, N = 512;
  const int wave = tid >> 6, lane = tid & 63;
  const int quad = lane >> 4, l15 = lane & 15;
  const int wm = wave >> 1, wn = wave & 1;
  const int n0 = (vb & 3) * 128, m0 = (vb >> 2) * 64;

  int arow[2], aoff[2], brow[4], boff[4];
#pragma unroll
  for (int c = 0; c < 2; ++c) {
    int u = c * 256 + tid;
    int slab = u >> 8, r2 = u & 255;
    arow[c] = r2 >> 2; aoff[c] = slab * 32 + (r2 & 3) * 8;
  }
#pragma unroll
  for (int c = 0; c < 4; ++c) {
    int u = c * 256 + tid;
    int slab = u >> 9, r2 = u & 511;
    brow[c] = r2 >> 2; boff[c] = slab * 32 + (r2 & 3) * 8;
  }

  fx4 acc[2][4];
#pragma unroll
  for (int i = 0; i < 2; ++i)
#pragma unroll
    for (int j = 0; j < 4; ++j) acc[i][j] = fx4{0.f, 0.f, 0.f, 0.f};

  bf16x8 apre[2], bpre[4];
#pragma unroll
  for (int c = 0; c < 2; ++c)
    apre[c] = *(const bf16x8*)(A + (size_t)(m0 + arow[c]) * K + aoff[c]);
#pragma unroll
  for (int c = 0; c < 4; ++c)
    bpre[c] = *(const bf16x8*)(Bt + (size_t)(n0 + brow[c]) * K + boff[c]);

  for (int k0 = 0; k0 < K; k0 += 64) {
    bar_raw();
#pragma unroll
    for (int c = 0; c < 2; ++c)
      *(bf16x8*)(As + (size_t)(c * 256 + tid) * 8) = apre[c];
#pragma unroll
    for (int c = 0; c < 4; ++c)
      *(bf16x8*)(Bs + (size_t)(c * 256 + tid) * 8) = bpre[c];
    {
      int kn = (k0 + 64) & 511;
#pragma unroll
      for (int c = 0; c < 2; ++c)
        apre[c] = *(const bf16x8*)(A + (size_t)(m0 + arow[c]) * K + kn + aoff[c]);
#pragma unroll
      for (int c = 0; c < 4; ++c)
        bpre[c] = *(const bf16x8*)(Bt + (size_t)(n0 + brow[c]) * K + kn + boff[c]);
    }
    bar_lgkm();

#pragma unroll
    for (int ks2 = 0; ks2 < 2; ++ks2) {
      bf16x8 af[2], bfr[4];
#pragma unroll
      for (int i = 0; i < 2; ++i)
        af[i] = *(const bf16x8*)(As + ks2 * 2048 + (wm * 32 + i * 16 + l15) * 32 + quad * 8);
#pragma unroll
      for (int i = 0; i < 4; ++i)
        bfr[i] = *(const bf16x8*)(Bs + ks2 * 4096 + (wn * 64 + i * 16 + l15) * 32 + quad * 8);
#pragma unroll
      for (int mi = 0; mi < 2; ++mi)
#pragma unroll
        for (int ni = 0; ni < 4; ++ni)
          acc[mi][ni] = __builtin_amdgcn_mfma_f32_16x16x32_bf16(af[mi], bfr[ni], acc[mi][ni], 0, 0, 0);
    }
  }

  const int rowb = m0 + wm * 32;
  const int colb = n0 + wn * 64;
#pragma unroll
  for (int mi = 0; mi < 2; ++mi)
#pragma unroll
    for (int ni = 0; ni < 4; ++ni) {
      int cg_ = colb + ni * 16 + l15;
      float bv = bias[cg_];
#pragma unroll
      for (int r = 0; r < 4; ++r) {
        int rg = rowb + mi * 16 + quad * 4 + r;
        of[(size_t)rg * N + cg_] = acc[mi][ni][r] + bv;
      }
    }
}

// =======================================================================
// ==================  Standalone kernels (R10 path)  ====================
// =======================================================================

__global__ __launch_bounds__(256) void prep_kernel(
    const float* __restrict__ x, const float* __restrict__ Wq,
    const float* __restrict__ Wkv, const float* __restrict__ Wo,
    short* __restrict__ xb, short* __restrict__ WallT, short* __restrict__ WoT,
    float qscale) {
  __shared__ float t[32][33];
  prep_body(blockIdx.x, threadIdx.x, (void*)t, x, Wq, Wkv, Wo, xb, WallT, WoT, qscale);
}

__global__ __launch_bounds__(256) void gemm_qkv(
    const short* __restrict__ A, const short* __restrict__ Bt,
    short* __restrict__ oq, short* __restrict__ ok, short* __restrict__ ovT) {
  __shared__ __align__(16) char smem[49152];
  qkv_body(blockIdx.x, threadIdx.x, smem, A, Bt, oq, ok, ovT);
}

__global__ __launch_bounds__(256, 2) void attn_kernel(
    const short* __restrict__ Q, const short* __restrict__ Kq,
    const short* __restrict__ Vt, short* __restrict__ O) {
  __shared__ __align__(16) char smem[32768];
  attn_body(blockIdx.x, threadIdx.x, smem, Q, Kq, Vt, O);
}

__global__ __launch_bounds__(256) void gemm_out(
    const short* __restrict__ A, const short* __restrict__ Bt,
    float* __restrict__ of, const float* __restrict__ bias) {
  __shared__ __align__(16) char smem[24576];
  out_body(blockIdx.y * 4 + blockIdx.x, threadIdx.x, smem, A, Bt, of, bias);
}

// =======================================================================
// ==================  Cooperative fused kernels  ========================
// =======================================================================

// K1: prep (grid-strided) -> grid.sync -> QKV GEMM. Grid 768, 3 blocks/CU.
__global__ __launch_bounds__(256, 3) void k_prep_qkv(
    const float* __restrict__ x, const float* __restrict__ Wq,
    const float* __restrict__ Wkv, const float* __restrict__ Wo,
    short* __restrict__ xb, short* __restrict__ WallT, short* __restrict__ WoT,
    float qscale,
    short* __restrict__ oq, short* __restrict__ ok, short* __restrict__ ovT) {
  __shared__ __align__(16) char smem[49152];
  const int tid = threadIdx.x;
  for (int vb = blockIdx.x; vb < 5120; vb += 768)
    prep_body(vb, tid, (void*)smem, x, Wq, Wkv, Wo, xb, WallT, WoT, qscale);
  __threadfence_system();
  cg::this_grid().sync();
  __threadfence_system();
  qkv_body(blockIdx.x, tid, smem, xb, WallT, oq, ok, ovT);
}

// K2: attn -> grid.sync -> out-proj. Grid 512, 2 blocks/CU.
__global__ __launch_bounds__(256, 2) void k_attn_out(
    const short* __restrict__ Q, const short* __restrict__ Kq,
    const short* __restrict__ Vt, short* __restrict__ O,
    const short* __restrict__ WoT, float* __restrict__ of,
    const float* __restrict__ bias) {
  __shared__ __align__(16) char smem[32768];
  const int tid = threadIdx.x;
  attn_body(blockIdx.x, tid, smem, Q, Kq, Vt, O);
  __threadfence_system();
  cg::this_grid().sync();
  __threadfence_system();
  out_body(blockIdx.x, tid, smem, O, WoT, of, bias);
}

// ---------- launch ----------
extern "C" void kernel_launch(void* const* d_in, const int* in_sizes, int n_in,
                              void* d_out, int out_size, void* d_ws, size_t ws_size,
                              hipStream_t stream) {
  const float* x   = (const float*)d_in[0];
  const float* Wq  = (const float*)d_in[1];
  const float* Wkv = (const float*)d_in[2];
  const float* Wo  = (const float*)d_in[3];
  const float* bo  = (const float*)d_in[4];
  float* out = (float*)d_out;

  char* p = (char*)d_ws;
  short* xb    = (short*)p; p += (size_t)8192 * 512 * 2;   // x bf16 [8192,512]
  short* WallT = (short*)p; p += (size_t)1536 * 512 * 2;   // [Wq|Wkv]^T bf16 [1536,512]
  short* WoT   = (short*)p; p += (size_t)512 * 512 * 2;    // Wo^T bf16 [512,512]
  short* qb    = (short*)p; p += (size_t)32 * 2048 * 64 * 2;  // [bh,n,d]
  short* kb    = (short*)p; p += (size_t)32 * 2048 * 64 * 2;  // [bh,n,d]
  short* vTb   = (short*)p; p += (size_t)32 * 64 * 2048 * 2;  // [bh,d,n]
  short* Ob    = (short*)p; p += (size_t)8192 * 512 * 2;   // attn out bf16 [8192,512]

  float qscale = 0.125f * 1.4426950408889634f;  // d^-0.5 * log2(e)

  // Try cooperative fusion once; on ANY launch error fall back permanently
  // to the proven R10 4-kernel chain (so later graph captures never attempt
  // a failing launch).
  static bool coop_ok = true;

  bool k1_coop = false;
  if (coop_ok) {
    void* a1[] = { (void*)&x, (void*)&Wq, (void*)&Wkv, (void*)&Wo,
                   (void*)&xb, (void*)&WallT, (void*)&WoT, (void*)&qscale,
                   (void*)&qb, (void*)&kb, (void*)&vTb };
    hipError_t e = hipLaunchCooperativeKernel((const void*)k_prep_qkv,
                                              dim3(768), dim3(256), a1, 0, stream);
    if (e == hipSuccess) k1_coop = true;
    else coop_ok = false;
  }
  if (!k1_coop) {
    prep_kernel<<<5120, 256, 0, stream>>>(x, Wq, Wkv, Wo, xb, WallT, WoT, qscale);
    gemm_qkv<<<768, 256, 0, stream>>>(xb, WallT, qb, kb, vTb);
  }

  bool k2_coop = false;
  if (coop_ok) {
    void* a2[] = { (void*)&qb, (void*)&kb, (void*)&vTb, (void*)&Ob,
                   (void*)&WoT, (void*)&out, (void*)&bo };
    hipError_t e = hipLaunchCooperativeKernel((const void*)k_attn_out,
                                              dim3(512), dim3(256), a2, 0, stream);
    if (e == hipSuccess) k2_coop = true;
    else coop_ok = false;
  }
  if (!k2_coop) {
    attn_kernel<<<512, 256, 0, stream>>>(qb, kb, vTb, Ob);
    gemm_out<<<dim3(4, 128), 256, 0, stream>>>(Ob, WoT, out, bo);
  }
}